// Round 6
// baseline (604.436 us; speedup 1.0000x reference)
//
#include <hip/hip_runtime.h>

// out = A @ x, A sparse COO (rows, cols, edge_vals), x [N,64] f32.
//
// Pipeline: counting-sort edges into 128-row buckets, then one block per
// bucket accumulates into a 32KB LDS accumulator and does one coalesced store.
//
// Scatter uses per-block LDS binning + block-reserved contiguous ranges so
// pair writes are block-private runs (mostly full 64B lines). Rounds 3-5
// showed any fine-grained global-cursor scatter degenerates to
// WRITE_SIZE == E*64B (partial lines shared across XCDs, ~100us).
//
// Reduce keeps round-4's proven LDS staging (coalesced pair loads) and adds
// dependency-free LDS f32 atomic accumulate (bank = lane%32, 2-way = free);
// round 5 proved un-staged global broadcast loads are latency-death.

#define D_FEAT   64
#define RPB      128            // rows per bucket
#define RPB_BITS 7
#define COL_BITS 17             // N=100000 < 2^17; rowlow in bits [17,24)
#define MAXB     800            // LDS array cap for bucket counts (782 used)
#define CHUNK_SC 8192           // edges per scatter chunk
#define BUF_RED  1024           // staged pairs per reduce chunk

// ---------------- fallback (round-1 kernel, 272us) ----------------
__global__ void spmv_coo_kernel(const float* __restrict__ x,
                                const int* __restrict__ rows,
                                const int* __restrict__ cols,
                                const float* __restrict__ ev,
                                float* __restrict__ out,
                                int n_edges) {
    const int lane = threadIdx.x & 63;
    const int wave_global = blockIdx.x * (blockDim.x >> 6) + (threadIdx.x >> 6);
    const int n_waves = gridDim.x * (blockDim.x >> 6);
    for (int e = wave_global; e < n_edges; e += n_waves) {
        atomicAdd(&out[rows[e] * D_FEAT + lane], ev[e] * x[cols[e] * D_FEAT + lane]);
    }
}

// ---------------- phase 1: bucket histogram (LDS-merged) ----------------
__global__ void hist_kernel(const int* __restrict__ rows, int* __restrict__ counts,
                            int n_edges, int n_buckets) {
    __shared__ int lh[MAXB];
    for (int i = threadIdx.x; i < n_buckets; i += blockDim.x) lh[i] = 0;
    __syncthreads();
    int gid = blockIdx.x * blockDim.x + threadIdx.x;
    int stride = gridDim.x * blockDim.x;
    for (int e = gid; e < n_edges; e += stride)
        atomicAdd(&lh[rows[e] >> RPB_BITS], 1);
    __syncthreads();
    for (int i = threadIdx.x; i < n_buckets; i += blockDim.x) {
        int c = lh[i];
        if (c) atomicAdd(&counts[i], c);
    }
}

// ---------------- phase 2: single-block scan (n_buckets <= 1024) ----------
__global__ void scan_kernel(const int* __restrict__ counts,
                            int* __restrict__ offsets, int* __restrict__ cursor,
                            int n_buckets, int n_edges) {
    __shared__ int s[1024];
    int t = threadIdx.x;
    int val = (t < n_buckets) ? counts[t] : 0;
    s[t] = val;
    __syncthreads();
    for (int off = 1; off < 1024; off <<= 1) {
        int tmp = (t >= off) ? s[t - off] : 0;
        __syncthreads();
        s[t] += tmp;
        __syncthreads();
    }
    if (t < n_buckets) {
        int v = s[t] - val;       // exclusive
        offsets[t] = v;
        cursor[t]  = v;
    }
    if (t == 0) offsets[n_buckets] = n_edges;
}

// ---------------- phase 3: scatter with per-block binning ----------------
// Each block: LDS-hist its chunk, reserve one contiguous global range per
// bucket (1 atomic per non-empty bucket), then write edges into the
// block-private ranges. Writes are ~CHUNK_SC/n_buckets-edge runs.
__global__ void __launch_bounds__(256) scatter_kernel(
        const int* __restrict__ rows, const int* __restrict__ cols,
        const float* __restrict__ ev, int* __restrict__ cursor,
        uint2* __restrict__ pairs, int n_edges, int n_buckets) {
    __shared__ int lh[MAXB];
    __shared__ int lbase[MAXB];
    const int t = threadIdx.x;
    const int nchunks = (n_edges + CHUNK_SC - 1) / CHUNK_SC;
    for (int ch = blockIdx.x; ch < nchunks; ch += gridDim.x) {
        const int s = ch * CHUNK_SC;
        const int e = min(s + CHUNK_SC, n_edges);
        for (int i = t; i < n_buckets; i += 256) lh[i] = 0;
        __syncthreads();
        for (int i = s + t; i < e; i += 256)
            atomicAdd(&lh[rows[i] >> RPB_BITS], 1);
        __syncthreads();
        for (int i = t; i < n_buckets; i += 256) {
            int c = lh[i];
            lbase[i] = c ? atomicAdd(&cursor[i], c) : 0;
            lh[i] = 0;            // reuse as local cursor
        }
        __syncthreads();
        for (int i = s + t; i < e; i += 256) {
            int r = rows[i];
            int b = r >> RPB_BITS;
            int pos = lbase[b] + atomicAdd(&lh[b], 1);
            uint2 p;
            p.x = (unsigned)cols[i] | ((unsigned)(r & (RPB - 1)) << COL_BITS);
            p.y = __float_as_uint(ev[i]);
            pairs[pos] = p;
        }
        __syncthreads();          // protect lh/lbase before next chunk
    }
}

// ---------------- phase 4: per-bucket reduction ----------------
// One block per 128-row bucket. Stage pairs coalesced to LDS; waves
// partition staged edges (i%4==w); gather x row coalesced; accumulate via
// LDS f32 atomics (no register dep chain -> iterations pipeline); single
// fully-coalesced 32KB store.
__global__ void __launch_bounds__(256) bucket_reduce_kernel(
        const float* __restrict__ x,
        const int* __restrict__ offsets,
        const uint2* __restrict__ pairs,
        float* __restrict__ out, int n_rows) {
    __shared__ float s_acc[RPB * D_FEAT];   // 32 KB
    __shared__ uint2 buf[BUF_RED];          // 8 KB
    const int t = threadIdx.x;
    const int lane = t & 63;
    const int w = t >> 6;                   // 0..3
    const int b = blockIdx.x;

    for (int i = t; i < RPB * D_FEAT; i += 256) s_acc[i] = 0.0f;

    const int s = offsets[b];
    const int e = offsets[b + 1];
    for (int base = s; base < e; base += BUF_RED) {
        const int cnt = min(BUF_RED, e - base);
        __syncthreads();
        for (int i = t; i < cnt; i += 256) buf[i] = pairs[base + i];
        __syncthreads();
        for (int i = w; i < cnt; i += 4) {
            const uint2 p = buf[i];                       // broadcast LDS read
            const int rl = (int)(p.x >> COL_BITS);        // 7-bit row-in-bucket
            const int c  = (int)(p.x & ((1u << COL_BITS) - 1));
            const float m = __uint_as_float(p.y) * x[c * D_FEAT + lane];
            atomicAdd(&s_acc[rl * D_FEAT + lane], m);     // ds_add_f32, 2-way bank
        }
    }
    __syncthreads();

    const int vbase = b * (RPB * D_FEAT);
    const int vmax  = n_rows * D_FEAT;
    for (int i = t; i < RPB * D_FEAT; i += 256) {
        const int gi = vbase + i;
        if (gi < vmax) out[gi] = s_acc[i];                // coalesced
    }
}

extern "C" void kernel_launch(void* const* d_in, const int* in_sizes, int n_in,
                              void* d_out, int out_size, void* d_ws, size_t ws_size,
                              hipStream_t stream) {
    const float* x    = (const float*)d_in[1];
    const int*   rows = (const int*)d_in[2];
    const int*   cols = (const int*)d_in[3];
    const float* ev   = (const float*)d_in[4];
    float* out = (float*)d_out;
    const int n_edges = in_sizes[3];
    const int n_rows  = out_size / D_FEAT;
    const int n_buckets = (n_rows + RPB - 1) / RPB;    // 782 for N=100K

    // workspace layout (bytes)
    size_t off_counts  = 0;
    size_t off_offsets = off_counts + (size_t)n_buckets * 4;
    size_t off_cursor  = off_offsets + ((size_t)n_buckets + 2) * 4;
    size_t off_pairs   = (off_cursor + (size_t)n_buckets * 4 + 7) & ~(size_t)7;
    size_t need = off_pairs + (size_t)n_edges * 8;

    if (ws_size < need || n_buckets > MAXB) {
        hipMemsetAsync(d_out, 0, (size_t)out_size * sizeof(float), stream);
        spmv_coo_kernel<<<4096, 256, 0, stream>>>(x, rows, cols, ev, out, n_edges);
        return;
    }

    char* ws = (char*)d_ws;
    int*   counts  = (int*)(ws + off_counts);
    int*   offsets = (int*)(ws + off_offsets);
    int*   cursor  = (int*)(ws + off_cursor);
    uint2* pairs   = (uint2*)(ws + off_pairs);

    hipMemsetAsync(counts, 0, (size_t)n_buckets * 4, stream);

    const int nchunks = (n_edges + CHUNK_SC - 1) / CHUNK_SC;   // 153

    hist_kernel<<<256, 256, 0, stream>>>(rows, counts, n_edges, n_buckets);
    scan_kernel<<<1, 1024, 0, stream>>>(counts, offsets, cursor, n_buckets, n_edges);
    scatter_kernel<<<nchunks, 256, 0, stream>>>(rows, cols, ev, cursor, pairs,
                                                n_edges, n_buckets);
    bucket_reduce_kernel<<<n_buckets, 256, 0, stream>>>(x, offsets, pairs, out, n_rows);
}

// Round 7
// 120.119 us; speedup vs baseline: 5.0320x; 5.0320x over previous
//
#include <hip/hip_runtime.h>

// out = A @ x, A sparse COO (rows, cols, edge_vals), x [N,64] f32.
//
// Pipeline:
//   1. hist+scan+block-binned scatter: counting-sort edges into 64-row
//      buckets (proven ~50us in round 6; block-private contiguous ranges
//      avoid the partial-line WRITE_SIZE=E*64B death of rounds 3-5).
//   2. fused sort_reduce: one block per bucket. Stage pairs in LDS ->
//      in-LDS counting sort by row (LDS hist, wave-shfl scan, LDS scatter)
//      -> each wave reduces its rows with REGISTER accumulators ->
//      coalesced store. No global atomics, no redundant scans.
//
// Hard-won rules: inner loop must accumulate in REGISTERS (LDS atomics
// serialize the DS pipe behind each gather's vmcnt wait: round 6, 550us;
// round 4 register version: 113us). Pair loads must be LDS-staged
// coalesced (round 5: raw global broadcast loads = 418us).

#define D_FEAT   64
#define RPB      64             // rows per bucket
#define RPB_BITS 6
#define COL_BITS 17             // col < 2^17; row-in-bucket in bits [17,23)
#define MAXB     1600           // >= n_buckets=1563
#define CHUNK_SC 8192           // edges per scatter chunk
#define CAP      1152           // LDS pair cap per bucket (mean 800, +12 sigma)

// ---------------- fallback (round-1 kernel) ----------------
__global__ void spmv_coo_kernel(const float* __restrict__ x,
                                const int* __restrict__ rows,
                                const int* __restrict__ cols,
                                const float* __restrict__ ev,
                                float* __restrict__ out,
                                int n_edges) {
    const int lane = threadIdx.x & 63;
    const int wave_global = blockIdx.x * (blockDim.x >> 6) + (threadIdx.x >> 6);
    const int n_waves = gridDim.x * (blockDim.x >> 6);
    for (int e = wave_global; e < n_edges; e += n_waves) {
        atomicAdd(&out[rows[e] * D_FEAT + lane], ev[e] * x[cols[e] * D_FEAT + lane]);
    }
}

// ---------------- phase 1: bucket histogram (LDS-merged) ----------------
__global__ void hist_kernel(const int* __restrict__ rows, int* __restrict__ counts,
                            int n_edges, int n_buckets) {
    __shared__ int lh[MAXB];
    for (int i = threadIdx.x; i < n_buckets; i += blockDim.x) lh[i] = 0;
    __syncthreads();
    int gid = blockIdx.x * blockDim.x + threadIdx.x;
    int stride = gridDim.x * blockDim.x;
    for (int e = gid; e < n_edges; e += stride)
        atomicAdd(&lh[rows[e] >> RPB_BITS], 1);
    __syncthreads();
    for (int i = threadIdx.x; i < n_buckets; i += blockDim.x) {
        int c = lh[i];
        if (c) atomicAdd(&counts[i], c);
    }
}

// ---------------- phase 2: single-block scan, 2 elems/thread (n<=2048) -----
__global__ void scan_kernel(const int* __restrict__ counts,
                            int* __restrict__ offsets, int* __restrict__ cursor,
                            int n, int n_edges) {
    __shared__ int s[1024];
    const int t = threadIdx.x;
    const int i0 = 2 * t, i1 = 2 * t + 1;
    int v0 = (i0 < n) ? counts[i0] : 0;
    int v1 = (i1 < n) ? counts[i1] : 0;
    s[t] = v0 + v1;
    __syncthreads();
    for (int off = 1; off < 1024; off <<= 1) {
        int tmp = (t >= off) ? s[t - off] : 0;
        __syncthreads();
        s[t] += tmp;
        __syncthreads();
    }
    int excl = s[t] - (v0 + v1);
    if (i0 < n) { offsets[i0] = excl;      cursor[i0] = excl; }
    if (i1 < n) { offsets[i1] = excl + v0; cursor[i1] = excl + v0; }
    if (t == 0) offsets[n] = n_edges;
}

// ---------------- phase 3: scatter with per-block LDS binning ----------------
__global__ void __launch_bounds__(256) scatter_kernel(
        const int* __restrict__ rows, const int* __restrict__ cols,
        const float* __restrict__ ev, int* __restrict__ cursor,
        uint2* __restrict__ pairs, int n_edges, int n_buckets) {
    __shared__ int lh[MAXB];
    __shared__ int lbase[MAXB];
    const int t = threadIdx.x;
    const int nchunks = (n_edges + CHUNK_SC - 1) / CHUNK_SC;
    for (int ch = blockIdx.x; ch < nchunks; ch += gridDim.x) {
        const int s = ch * CHUNK_SC;
        const int e = min(s + CHUNK_SC, n_edges);
        for (int i = t; i < n_buckets; i += 256) lh[i] = 0;
        __syncthreads();
        for (int i = s + t; i < e; i += 256)
            atomicAdd(&lh[rows[i] >> RPB_BITS], 1);
        __syncthreads();
        for (int i = t; i < n_buckets; i += 256) {
            int c = lh[i];
            lbase[i] = c ? atomicAdd(&cursor[i], c) : 0;
            lh[i] = 0;            // reuse as local cursor
        }
        __syncthreads();
        for (int i = s + t; i < e; i += 256) {
            int r = rows[i];
            int b = r >> RPB_BITS;
            int pos = lbase[b] + atomicAdd(&lh[b], 1);
            uint2 p;
            p.x = (unsigned)cols[i] | ((unsigned)(r & (RPB - 1)) << COL_BITS);
            p.y = __float_as_uint(ev[i]);
            pairs[pos] = p;
        }
        __syncthreads();
    }
}

// ---------------- phase 4: fused in-LDS row-sort + register reduce ----------
__global__ void __launch_bounds__(256) sort_reduce_kernel(
        const float* __restrict__ x,
        const int* __restrict__ offsets,
        const uint2* __restrict__ pairs,
        float* __restrict__ out, int n_rows) {
    __shared__ uint2 buf[CAP];      // 9.2 KB staged pairs
    __shared__ uint2 srt[CAP];      // 9.2 KB row-sorted pairs
    __shared__ int   hist[RPB + 1]; // becomes row_ptr
    __shared__ int   lcur[RPB];
    const int t = threadIdx.x;
    const int lane = t & 63;
    const int w = t >> 6;           // 0..3
    const int b = blockIdx.x;
    const int s = offsets[b];
    const int e = offsets[b + 1];
    const int cnt = e - s;

    if (cnt <= CAP) {
        if (t <= RPB) hist[t] = 0;
        __syncthreads();
        // stage + histogram rows
        for (int i = t; i < cnt; i += 256) {
            uint2 p = pairs[s + i];                     // coalesced
            buf[i] = p;
            atomicAdd(&hist[1 + (int)(p.x >> COL_BITS)], 1);
        }
        __syncthreads();
        // wave 0: inclusive shfl-scan of hist[1..RPB] -> row_ptr; init lcur
        if (w == 0) {
            int v = hist[1 + lane];
            for (int d = 1; d < 64; d <<= 1) {
                int n = __shfl_up(v, d);
                if (lane >= d) v += n;
            }
            hist[1 + lane] = v;
        }
        __syncthreads();
        if (w == 0) lcur[lane] = hist[lane];            // exclusive starts
        __syncthreads();
        // in-LDS scatter into row-sorted order
        for (int i = t; i < cnt; i += 256) {
            uint2 p = buf[i];
            int rl = (int)(p.x >> COL_BITS);
            int pos = atomicAdd(&lcur[rl], 1);
            srt[pos] = p;
        }
        __syncthreads();
        // register-accumulating reduce; wave w owns rows w, w+4, ...
        for (int r = w; r < RPB; r += 4) {
            const int rs = hist[r];
            const int re = hist[r + 1];
            float acc0 = 0.0f, acc1 = 0.0f;
            int j = rs;
            for (; j + 2 <= re; j += 2) {
                const uint2 p0 = srt[j];
                const uint2 p1 = srt[j + 1];
                const int c0 = (int)(p0.x & ((1u << COL_BITS) - 1));
                const int c1 = (int)(p1.x & ((1u << COL_BITS) - 1));
                acc0 += __uint_as_float(p0.y) * x[c0 * D_FEAT + lane];
                acc1 += __uint_as_float(p1.y) * x[c1 * D_FEAT + lane];
            }
            if (j < re) {
                const uint2 p0 = srt[j];
                const int c0 = (int)(p0.x & ((1u << COL_BITS) - 1));
                acc0 += __uint_as_float(p0.y) * x[c0 * D_FEAT + lane];
            }
            const int row = b * RPB + r;
            if (row < n_rows) out[row * D_FEAT + lane] = acc0 + acc1;
        }
    } else {
        // overflow bucket (statistically never at E/buckets=800, cap 1152):
        // zero owned rows, then chunked stage + global-atomic accumulate.
        for (int r = w; r < RPB; r += 4) {
            const int row = b * RPB + r;
            if (row < n_rows) out[row * D_FEAT + lane] = 0.0f;
        }
        __syncthreads();
        for (int base = s; base < e; base += CAP) {
            const int c2 = min(CAP, e - base);
            for (int i = t; i < c2; i += 256) buf[i] = pairs[base + i];
            __syncthreads();
            for (int i = w; i < c2; i += 4) {
                const uint2 p = buf[i];
                const int rl = (int)(p.x >> COL_BITS);
                const int c  = (int)(p.x & ((1u << COL_BITS) - 1));
                const float m = __uint_as_float(p.y) * x[c * D_FEAT + lane];
                atomicAdd(&out[(b * RPB + rl) * D_FEAT + lane], m);
            }
            __syncthreads();
        }
    }
}

extern "C" void kernel_launch(void* const* d_in, const int* in_sizes, int n_in,
                              void* d_out, int out_size, void* d_ws, size_t ws_size,
                              hipStream_t stream) {
    const float* x    = (const float*)d_in[1];
    const int*   rows = (const int*)d_in[2];
    const int*   cols = (const int*)d_in[3];
    const float* ev   = (const float*)d_in[4];
    float* out = (float*)d_out;
    const int n_edges = in_sizes[3];
    const int n_rows  = out_size / D_FEAT;
    const int n_buckets = (n_rows + RPB - 1) / RPB;    // 1563 for N=100K

    // workspace layout (bytes)
    size_t off_counts  = 0;
    size_t off_offsets = off_counts + (size_t)n_buckets * 4;
    size_t off_cursor  = off_offsets + ((size_t)n_buckets + 2) * 4;
    size_t off_pairs   = (off_cursor + (size_t)n_buckets * 4 + 7) & ~(size_t)7;
    size_t need = off_pairs + (size_t)n_edges * 8;

    if (ws_size < need || n_buckets > MAXB || n_buckets > 2048) {
        hipMemsetAsync(d_out, 0, (size_t)out_size * sizeof(float), stream);
        spmv_coo_kernel<<<4096, 256, 0, stream>>>(x, rows, cols, ev, out, n_edges);
        return;
    }

    char* ws = (char*)d_ws;
    int*   counts  = (int*)(ws + off_counts);
    int*   offsets = (int*)(ws + off_offsets);
    int*   cursor  = (int*)(ws + off_cursor);
    uint2* pairs   = (uint2*)(ws + off_pairs);

    hipMemsetAsync(counts, 0, (size_t)n_buckets * 4, stream);

    const int nchunks = (n_edges + CHUNK_SC - 1) / CHUNK_SC;   // 153

    hist_kernel<<<256, 256, 0, stream>>>(rows, counts, n_edges, n_buckets);
    scan_kernel<<<1, 1024, 0, stream>>>(counts, offsets, cursor, n_buckets, n_edges);
    scatter_kernel<<<nchunks, 256, 0, stream>>>(rows, cols, ev, cursor, pairs,
                                                n_edges, n_buckets);
    sort_reduce_kernel<<<n_buckets, 256, 0, stream>>>(x, offsets, pairs, out, n_rows);
}